// Round 8
// baseline (314.438 us; speedup 1.0000x reference)
//
#include <hip/hip_runtime.h>
#include <hip/hip_bf16.h>
#include <stdint.h>

#define M_ROWS 8192
#define K_DIM  4096
#define N_DIM  4096

using bf16 = __hip_bfloat16;
typedef __attribute__((ext_vector_type(4)))  float f32x4;
typedef __attribute__((ext_vector_type(16))) float f32x16;
typedef __attribute__((ext_vector_type(8)))  short s16x8;

__device__ __forceinline__ void gll16(const bf16* g, bf16* l) {
  __builtin_amdgcn_global_load_lds(
      (const __attribute__((address_space(1))) void*)g,
      (__attribute__((address_space(3))) void*)l, 16, 0, 0);
}

// ===========================================================================
// PATH A: BK=32 chunks, swizzle baked into global panel layout (UNCHANGED
// from round 7 — only the GEMM's read addressing / MFMA shape changed).
// A panels: chunk[tm*128+kt] of 4096 bf16 = [row128][slot4][8]
//   data(row,ss)[j] = x[tm*128+row][kt*32 + (ss^((row>>1)&3))*8 + j]
// B panels: chunk[tn*128+kt] of 8192 bf16 = [col256][slot4][8]
//   data(col,ss)[j] = W[kt*32 + (ss^((col>>1)&3))*8 + j][tn*256+col]
// ===========================================================================
__global__ __launch_bounds__(256) void prep_k(
    const int* __restrict__ qw, const float* __restrict__ s1,
    const float* __restrict__ s2, const float* __restrict__ x,
    bf16* __restrict__ Bp, bf16* __restrict__ Ap)
{
  const int bid = blockIdx.x;
  if (bid < 2048) {
    const int t = bid * 256 + threadIdx.x;   // 0..524287
    const int o = t & 4095;
    const int q = t >> 12;          // kt 0..127
    const int r0 = q << 2;
    const int g = r0 >> 4;
    const int nt = o >> 8, col = o & 255;
    const int sw = (col >> 1) & 3;
    const float a = s1[g * 4096 + o] * 0.5f;   // codes >= 0 (q>=8)
    const float b = s2[g * 4096 + o] * 0.5f;   // codes <  0
    const uint64_t lo = 0x00FFFEFDFCFAF8F4ull;  // 2*CODE, q=0..7
    const uint64_t hi = 0x0C08060403020100ull;  // 2*CODE, q=8..15
    bf16* dst = Bp + (((size_t)(nt * 128 + q)) << 13) + col * 32;
    #pragma unroll
    for (int j = 0; j < 4; ++j) {
      const uint32_t wbits = (uint32_t)qw[(size_t)(r0 + j) * 4096 + o];
      union { bf16 h[8]; s16x8 v; } u;
      #pragma unroll
      for (int i = 0; i < 8; ++i) {
        const int qc = (wbits >> (4 * i)) & 15;
        const uint64_t pk = (qc & 8) ? hi : lo;
        const int c2 = (int)(int8_t)(uint8_t)(pk >> ((qc & 7) * 8));
        const float sc = (qc & 8) ? a : b;
        u.h[i] = __float2bfloat16((float)c2 * sc);
      }
      *(s16x8*)(dst + ((j ^ sw) << 3)) = u.v;
    }
  } else {
    const int t = (bid - 2048) * 256 + threadIdx.x;   // 0..4194303
    const int k8 = t & 511;
    const int kt = k8 >> 2;
    const int s_lin = k8 & 3;
    const int m  = t >> 9;
    const int tm = m >> 7, row = m & 127;
    const float* s = x + (size_t)m * 4096 + k8 * 8;
    f32x4 v0 = *(const f32x4*)s;
    f32x4 v1 = *(const f32x4*)(s + 4);
    union { bf16 h[8]; s16x8 v; } u;
    #pragma unroll
    for (int j = 0; j < 4; ++j) {
      u.h[j]     = __float2bfloat16(v0[j]);
      u.h[4 + j] = __float2bfloat16(v1[j]);
    }
    const int ss = s_lin ^ ((row >> 1) & 3);
    bf16* dst = Ap + (((size_t)(tm * 128 + kt)) << 12) + row * 32 + ss * 8;
    *(s16x8*)dst = u.v;
  }
}

// ---------------------------------------------------------------------------
// 128x256 GEMM, BK=32, 8 waves (2Mx4N, 64x64/wave as 2x2 of 32x32 frags),
// mfma_f32_32x32x16_bf16 (2495 TF ceiling vs 2176 for 16x16).
// __launch_bounds__(512,4), 3-buf LDS 72 KiB, 2 blocks/CU.
// ONE barrier per K-tile: reads(t) need end-BAR(t-1); MFMA needs own lgkm0;
// WAR on buf[(t+2)%3] is 3 tiles deep (reads drained by MFMA deps before
// each wave's end-BAR). Ledger unchanged from r7: entering t {C(t+1)}=3;
// +C(t+2)->6; VMW(3) clears C(t+1); BAR publishes. Peak 6 glls (<8 limit).
// Fragment maps: A row=lane&31,k=(lane>>5)*8+j; B col=lane&31 same k;
// D col=lane&31,row=(reg&3)+8*(reg>>2)+4*(lane>>5)  [m74/m101].
// ---------------------------------------------------------------------------
#define BAR()                                                         \
    asm volatile("s_barrier" ::: "memory");                           \
    __builtin_amdgcn_sched_barrier(0)

#define LGKM0()                                                       \
    asm volatile("s_waitcnt lgkmcnt(0)" ::: "memory");                \
    __builtin_amdgcn_sched_barrier(0)

#define VMW(N)                                                        \
    asm volatile("s_waitcnt vmcnt(" #N ")" ::: "memory");             \
    __builtin_amdgcn_sched_barrier(0)

#define KT9(BUF, KTN, PRE, VM)                                        \
  {                                                                   \
    const bf16* L_ = &lds[BUF][0];                                    \
    s16x8 afr[2][2], bbr[2][2];                                       \
    _Pragma("unroll")                                                 \
    for (int m = 0; m < 2; ++m)                                       \
      _Pragma("unroll")                                               \
      for (int kk = 0; kk < 2; ++kk)                                  \
        afr[m][kk] = *(const s16x8*)(L_ + abase + m * 1024 + soff[kk]); \
    _Pragma("unroll")                                                 \
    for (int n = 0; n < 2; ++n)                                       \
      _Pragma("unroll")                                               \
      for (int kk = 0; kk < 2; ++kk)                                  \
        bbr[n][kk] = *(const s16x8*)(L_ + bbase + n * 1024 + soff[kk]); \
    if (PRE) stage((KTN), ((BUF) + 2) % 3);                           \
    LGKM0();                                                          \
    __builtin_amdgcn_s_setprio(1);                                    \
    _Pragma("unroll")                                                 \
    for (int kk = 0; kk < 2; ++kk)                                    \
      _Pragma("unroll")                                               \
      for (int m = 0; m < 2; ++m)                                     \
        _Pragma("unroll")                                             \
        for (int n = 0; n < 2; ++n)                                   \
          acc[m][n] = __builtin_amdgcn_mfma_f32_32x32x16_bf16(        \
              afr[m][kk], bbr[n][kk], acc[m][n], 0, 0, 0);            \
    __builtin_amdgcn_s_setprio(0);                                    \
    VMW(VM);                                                          \
    BAR();                                                            \
  }

__global__ __launch_bounds__(512, 4) void gemm9_k(
    const bf16* __restrict__ Ap, const bf16* __restrict__ Bp,
    const float* __restrict__ bias, float* __restrict__ out)
{
  __shared__ bf16 lds[3][12288];   // [buf][A 4096 | B 8192]  72 KiB

  const int id  = blockIdx.x;      // 1024 blocks
  const int xcd = id & 7, lid = id >> 3;
  const int tn  = lid >> 3;                 // 0..15
  const int tm  = xcd * 8 + (lid & 7);      // 0..63  (bijective)
  const int tid = (int)threadIdx.x;
  const int lane = tid & 63;
  const int w    = tid >> 6;
  const int wr   = w >> 2;        // 0..1
  const int wc   = w & 3;         // 0..3
  const int lr32 = lane & 31;
  const int hi   = lane >> 5;
  const int sx   = (lr32 >> 1) & 3;
  int soff[2];
  soff[0] = ((0 * 2 + hi) ^ sx) * 8;
  soff[1] = ((1 * 2 + hi) ^ sx) * 8;
  const int abase = (wr * 64 + lr32) * 32;
  const int bbase = 4096 + (wc * 64 + lr32) * 32;

  const bf16* Abase = Ap + ((size_t)tm << 19);   // tm*128*4096
  const bf16* Bbase = Bp + ((size_t)tn << 20);   // tn*128*8192

  f32x16 acc[2][2];
  #pragma unroll
  for (int m = 0; m < 2; ++m)
    #pragma unroll
    for (int n = 0; n < 2; ++n)
      #pragma unroll
      for (int r = 0; r < 16; ++r) acc[m][n][r] = 0.f;

  auto stage = [&](int kt, int buf) {
    gll16(Abase + ((size_t)kt << 12) + tid * 8, &lds[buf][tid * 8]);
    const bf16* bs = Bbase + ((size_t)kt << 13) + tid * 8;
    gll16(bs,        &lds[buf][4096 + tid * 8]);
    gll16(bs + 4096, &lds[buf][8192 + tid * 8]);
  };

  // prologue: C0 -> buf0, C1 -> buf1 (6 glls); clear C0; publish
  stage(0, 0);
  stage(1, 1);
  VMW(3);
  BAR();

  #pragma unroll 1
  for (int t3 = 0; t3 < 42; ++t3) {
    KT9(0, 3 * t3 + 2, 1, 3);
    KT9(1, 3 * t3 + 3, 1, 3);
    KT9(2, 3 * t3 + 4, 1, 3);
  }
  KT9(0, 0, 0, 0);   // t=126: drain
  KT9(1, 0, 0, 0);   // t=127

  // epilogue: D col=lane&31, row=(r&3)+8*(r>>2)+4*(lane>>5)
  const int orow0 = tm * 128 + wr * 64 + hi * 4;
  const int ocol0 = tn * 256 + wc * 64 + lr32;
  #pragma unroll
  for (int m = 0; m < 2; ++m) {
    #pragma unroll
    for (int n = 0; n < 2; ++n) {
      const int col = ocol0 + n * 32;
      const float bv = bias[col];
      #pragma unroll
      for (int r = 0; r < 16; ++r) {
        const int row = orow0 + m * 32 + (r & 3) + 8 * (r >> 2);
        out[(size_t)row * N_DIM + col] = acc[m][n][r] + bv;
      }
    }
  }
}

// ===========================================================================
// PATH B fallback (round-1 verified): 128^2 tile, fp32 A reg-staged.
// ===========================================================================
__global__ __launch_bounds__(256) void dequant_f(
    const int* __restrict__ qw, const float* __restrict__ s1,
    const float* __restrict__ s2, bf16* __restrict__ Bp)
{
  const int t = blockIdx.x * 256 + threadIdx.x;
  const int o = t & 4095;
  const int r = t >> 12;
  const int g = r >> 4;
  const int kt = r >> 2;
  const int kk0 = (r & 3) * 8;
  const uint32_t wbits = (uint32_t)qw[(size_t)r * 4096 + o];
  const float a = s1[g * 4096 + o] * 0.5f;
  const float b = s2[g * 4096 + o] * 0.5f;
  const uint64_t lo = 0x00FFFEFDFCFAF8F4ull;
  const uint64_t hi = 0x0C08060403020100ull;
  union { bf16 h[8]; s16x8 v; } u;
  #pragma unroll
  for (int j = 0; j < 8; ++j) {
    const int q = (wbits >> (4 * j)) & 15;
    const uint64_t pk = (q & 8) ? hi : lo;
    const int c2 = (int)(int8_t)(uint8_t)(pk >> ((q & 7) * 8));
    const float s = (q & 8) ? a : b;
    u.h[j] = __float2bfloat16((float)c2 * s);
  }
  const int nt = o >> 7, col = o & 127;
  bf16* dst = Bp + (((size_t)(nt * 128 + kt) * 128 + col) * 32 + kk0);
  *(s16x8*)dst = u.v;
}

__global__ __launch_bounds__(256) void gemmf_k(
    const float* __restrict__ x, const bf16* __restrict__ Bp,
    const float* __restrict__ bias, float* __restrict__ out)
{
  __shared__ bf16 As[2][4096];
  __shared__ bf16 Bs[2][4096];

  const int id  = blockIdx.x;
  const int swz = (id & 7) * 256 + (id >> 3);
  const int tm  = swz >> 5;
  const int tn  = swz & 31;
  const int tid = threadIdx.x;
  const int lane = tid & 63;
  const int w   = tid >> 6;
  const int wr  = (w >> 1) * 64;
  const int wc  = (w & 1) * 64;
  const int lr  = lane & 15;
  const int lg  = lane >> 4;

  f32x4 acc[4][4];
  #pragma unroll
  for (int m = 0; m < 4; ++m)
    #pragma unroll
    for (int n = 0; n < 4; ++n) acc[m][n] = (f32x4){0.f, 0.f, 0.f, 0.f};

  const bf16* bsrc = Bp + ((size_t)tn << 19);
  const float* asrc_f = x + ((size_t)(tm * 128 + (tid >> 1)) << 12) + (tid & 1) * 16;
  float areg[16];

  auto stageB = [&](int kt, int buf) {
    const bf16* bs = bsrc + ((size_t)kt << 12);
    gll16(bs + tid * 8,        &Bs[buf][tid * 8]);
    gll16(bs + 2048 + tid * 8, &Bs[buf][2048 + tid * 8]);
  };
  auto loadA = [&](int kt) {
    const float* s = asrc_f + ((size_t)kt << 5);
    #pragma unroll
    for (int i = 0; i < 4; ++i)
      *(f32x4*)(areg + i * 4) = *(const f32x4*)(s + i * 4);
  };
  auto writeA = [&](int buf) {
    union { bf16 h[16]; s16x8 v[2]; } u;
    #pragma unroll
    for (int i = 0; i < 16; ++i) u.h[i] = __float2bfloat16(areg[i]);
    bf16* d = &As[buf][(tid >> 1) * 32 + (tid & 1) * 16];
    *(s16x8*)d = u.v[0];
    *(s16x8*)(d + 8) = u.v[1];
  };
  auto compute = [&](int buf) {
    s16x8 af[4], bv[4];
    #pragma unroll
    for (int m = 0; m < 4; ++m)
      af[m] = *(const s16x8*)(&As[buf][(wr + m * 16 + lr) * 32 + lg * 8]);
    #pragma unroll
    for (int n = 0; n < 4; ++n)
      bv[n] = *(const s16x8*)(&Bs[buf][(wc + n * 16 + lr) * 32 + lg * 8]);
    #pragma unroll
    for (int m = 0; m < 4; ++m)
      #pragma unroll
      for (int n = 0; n < 4; ++n)
        acc[m][n] = __builtin_amdgcn_mfma_f32_16x16x32_bf16(af[m], bv[n],
                                                            acc[m][n], 0, 0, 0);
  };

  stageB(0, 0);
  loadA(0);
  writeA(0);
  __syncthreads();

  #pragma unroll 2
  for (int kt = 0; kt < 128; ++kt) {
    const int buf = kt & 1;
    if (kt + 1 < 128) {
      stageB(kt + 1, buf ^ 1);
      loadA(kt + 1);
    }
    compute(buf);
    if (kt + 1 < 128) writeA(buf ^ 1);
    __syncthreads();
  }

  const int orow0 = tm * 128 + wr + lg * 4;
  const int ocol0 = tn * 128 + wc + lr;
  float bvv[4];
  #pragma unroll
  for (int n = 0; n < 4; ++n) bvv[n] = bias[ocol0 + n * 16];
  #pragma unroll
  for (int m = 0; m < 4; ++m) {
    #pragma unroll
    for (int r = 0; r < 4; ++r) {
      float* op = out + (size_t)(orow0 + m * 16 + r) * N_DIM + ocol0;
      #pragma unroll
      for (int n = 0; n < 4; ++n)
        op[n * 16] = acc[m][n][r] + bvv[n];
    }
  }
}

extern "C" void kernel_launch(void* const* d_in, const int* in_sizes, int n_in,
                              void* d_out, int out_size, void* d_ws, size_t ws_size,
                              hipStream_t stream) {
  const float* x    = (const float*)d_in[0];
  const int*   qw   = (const int*)d_in[1];
  const float* s1   = (const float*)d_in[2];
  const float* s2   = (const float*)d_in[3];
  const float* bias = (const float*)d_in[4];
  float* out = (float*)d_out;

  const size_t BP_BYTES = (size_t)K_DIM * N_DIM * 2;    // 32 MiB
  const size_t XB_BYTES = (size_t)M_ROWS * K_DIM * 2;   // 64 MiB
  bf16* Bp = (bf16*)d_ws;

  if (ws_size >= BP_BYTES + XB_BYTES) {
    bf16* Ap = (bf16*)((char*)d_ws + BP_BYTES);
    prep_k<<<dim3(18432), dim3(256), 0, stream>>>(qw, s1, s2, x, Bp, Ap);
    gemm9_k<<<dim3(1024), dim3(512), 0, stream>>>(Ap, Bp, bias, out);
  } else {
    dequant_f<<<dim3(8192), dim3(256), 0, stream>>>(qw, s1, s2, Bp);
    gemmf_k<<<dim3(2048), dim3(256), 0, stream>>>(x, Bp, bias, out);
  }
}

// Round 9
// 267.521 us; speedup vs baseline: 1.1754x; 1.1754x over previous
//
#include <hip/hip_runtime.h>
#include <hip/hip_bf16.h>
#include <stdint.h>

#define M_ROWS 8192
#define K_DIM  4096
#define N_DIM  4096

using bf16 = __hip_bfloat16;
typedef __attribute__((ext_vector_type(4))) float f32x4;
typedef __attribute__((ext_vector_type(8))) short s16x8;

__device__ __forceinline__ void gll16(const bf16* g, bf16* l) {
  __builtin_amdgcn_global_load_lds(
      (const __attribute__((address_space(1))) void*)g,
      (__attribute__((address_space(3))) void*)l, 16, 0, 0);
}

// ===========================================================================
// PATH A: BK=32 chunks, swizzle baked into global panel layout (r7-exact).
// A panels: chunk[tm*128+kt] of 4096 bf16 = [row128][slot4][8]
//   data(row,ss)[j] = x[tm*128+row][kt*32 + (ss^((row>>1)&3))*8 + j]
// B panels: chunk[tn*128+kt] of 8192 bf16 = [col256][slot4][8]
//   data(col,ss)[j] = W[kt*32 + (ss^((col>>1)&3))*8 + j][tn*256+col]
// Fused pre-pass: blocks [0,2048) dequant W -> Bp, [2048,18432) cast x -> Ap.
// ===========================================================================
__global__ __launch_bounds__(256) void prep_k(
    const int* __restrict__ qw, const float* __restrict__ s1,
    const float* __restrict__ s2, const float* __restrict__ x,
    bf16* __restrict__ Bp, bf16* __restrict__ Ap)
{
  const int bid = blockIdx.x;
  if (bid < 2048) {
    const int t = bid * 256 + threadIdx.x;   // 0..524287
    const int o = t & 4095;
    const int q = t >> 12;          // kt 0..127
    const int r0 = q << 2;
    const int g = r0 >> 4;
    const int nt = o >> 8, col = o & 255;
    const int sw = (col >> 1) & 3;
    const float a = s1[g * 4096 + o] * 0.5f;   // codes >= 0 (q>=8)
    const float b = s2[g * 4096 + o] * 0.5f;   // codes <  0
    const uint64_t lo = 0x00FFFEFDFCFAF8F4ull;  // 2*CODE, q=0..7
    const uint64_t hi = 0x0C08060403020100ull;  // 2*CODE, q=8..15
    bf16* dst = Bp + (((size_t)(nt * 128 + q)) << 13) + col * 32;
    #pragma unroll
    for (int j = 0; j < 4; ++j) {
      const uint32_t wbits = (uint32_t)qw[(size_t)(r0 + j) * 4096 + o];
      union { bf16 h[8]; s16x8 v; } u;
      #pragma unroll
      for (int i = 0; i < 8; ++i) {
        const int qc = (wbits >> (4 * i)) & 15;
        const uint64_t pk = (qc & 8) ? hi : lo;
        const int c2 = (int)(int8_t)(uint8_t)(pk >> ((qc & 7) * 8));
        const float sc = (qc & 8) ? a : b;
        u.h[i] = __float2bfloat16((float)c2 * sc);
      }
      *(s16x8*)(dst + ((j ^ sw) << 3)) = u.v;
    }
  } else {
    const int t = (bid - 2048) * 256 + threadIdx.x;   // 0..4194303
    const int k8 = t & 511;
    const int kt = k8 >> 2;
    const int s_lin = k8 & 3;
    const int m  = t >> 9;
    const int tm = m >> 7, row = m & 127;
    const float* s = x + (size_t)m * 4096 + k8 * 8;
    f32x4 v0 = *(const f32x4*)s;
    f32x4 v1 = *(const f32x4*)(s + 4);
    union { bf16 h[8]; s16x8 v; } u;
    #pragma unroll
    for (int j = 0; j < 4; ++j) {
      u.h[j]     = __float2bfloat16(v0[j]);
      u.h[4 + j] = __float2bfloat16(v1[j]);
    }
    const int ss = s_lin ^ ((row >> 1) & 3);
    bf16* dst = Ap + (((size_t)(tm * 128 + kt)) << 12) + row * 32 + ss * 8;
    *(s16x8*)dst = u.v;
  }
}

// ---------------------------------------------------------------------------
// 128x256 GEMM, BK=32, 8 waves (2Mx4N, 64x64/wave), 16x16x32 MFMA (r7-exact
// read pattern, verified 0 bank conflicts). __launch_bounds__(512,4),
// 3-buf LDS 72 KiB, 2 blocks/CU.
// ONE barrier per tile, COMPILER-managed lgkm waits:
//   reads(buf) ; stage(buf+2) ; MFMAs (data-dep lgkmcnt) ; VMW(3) ; BAR.
// WAR proof: each wave's reads drain via MFMA data-deps before its end-BAR;
// stage(t+1) into buf t%3 executes only after all waves passed end-BAR(t).
// Ledger (r7-proven): entering t {C(t+1)}=3; +C(t+2)->6; VMW(3) clears
// C(t+1); BAR publishes. Peak 6 glls (<8 limit).
// ---------------------------------------------------------------------------
#define BAR()                                                         \
    asm volatile("s_barrier" ::: "memory");                           \
    __builtin_amdgcn_sched_barrier(0)

#define VMW(N)                                                        \
    asm volatile("s_waitcnt vmcnt(" #N ")" ::: "memory");             \
    __builtin_amdgcn_sched_barrier(0)

#define KT9(BUF, KTN, PRE, VM)                                        \
  {                                                                   \
    const bf16* L_ = &lds[BUF][0];                                    \
    _Pragma("unroll")                                                 \
    for (int m = 0; m < 4; ++m) af[m] = *(const s16x8*)(L_ + aoff + m * 512); \
    _Pragma("unroll")                                                 \
    for (int n = 0; n < 4; ++n) bb[n] = *(const s16x8*)(L_ + boff + n * 512); \
    if (PRE) stage((KTN), ((BUF) + 2) % 3);                           \
    __builtin_amdgcn_s_setprio(1);                                    \
    _Pragma("unroll")                                                 \
    for (int m = 0; m < 4; ++m) {                                     \
      _Pragma("unroll")                                               \
      for (int n = 0; n < 4; ++n)                                     \
        acc[m][n] = __builtin_amdgcn_mfma_f32_16x16x32_bf16(          \
            af[m], bb[n], acc[m][n], 0, 0, 0);                        \
    }                                                                 \
    __builtin_amdgcn_s_setprio(0);                                    \
    VMW(VM);                                                          \
    BAR();                                                            \
  }

__global__ __launch_bounds__(512, 4) void gemm9_k(
    const bf16* __restrict__ Ap, const bf16* __restrict__ Bp,
    const float* __restrict__ bias, float* __restrict__ out)
{
  __shared__ bf16 lds[3][12288];   // [buf][A 4096 | B 8192]  72 KiB

  const int id  = blockIdx.x;      // 1024 blocks
  const int xcd = id & 7, lid = id >> 3;
  const int tn  = lid >> 3;                 // 0..15
  const int tm  = xcd * 8 + (lid & 7);      // 0..63  (bijective)
  const int tid = (int)threadIdx.x;
  const int lane = tid & 63;
  const int w   = tid >> 6;
  const int wr  = w >> 2;        // 0..1
  const int wc  = w & 3;         // 0..3
  const int lr  = lane & 15;
  const int lg  = lane >> 4;
  const int sl  = (lg ^ ((lr >> 1) & 3)) << 3;          // swizzled slot
  const int aoff = (wr * 64 + lr) * 32 + sl;
  const int boff = 4096 + (wc * 64 + lr) * 32 + sl;

  const bf16* Abase = Ap + ((size_t)tm << 19);   // tm*128*4096
  const bf16* Bbase = Bp + ((size_t)tn << 20);   // tn*128*8192

  f32x4 acc[4][4];
  #pragma unroll
  for (int m = 0; m < 4; ++m)
    #pragma unroll
    for (int n = 0; n < 4; ++n) acc[m][n] = (f32x4){0.f, 0.f, 0.f, 0.f};

  auto stage = [&](int kt, int buf) {
    gll16(Abase + ((size_t)kt << 12) + tid * 8, &lds[buf][tid * 8]);
    const bf16* bs = Bbase + ((size_t)kt << 13) + tid * 8;
    gll16(bs,        &lds[buf][4096 + tid * 8]);
    gll16(bs + 4096, &lds[buf][8192 + tid * 8]);
  };

  s16x8 af[4], bb[4];

  // prologue: C0 -> buf0, C1 -> buf1 (6 glls); clear C0; publish
  stage(0, 0);
  stage(1, 1);
  VMW(3);
  BAR();

  #pragma unroll 1
  for (int t3 = 0; t3 < 42; ++t3) {
    KT9(0, 3 * t3 + 2, 1, 3);
    KT9(1, 3 * t3 + 3, 1, 3);
    KT9(2, 3 * t3 + 4, 1, 3);
  }
  KT9(0, 0, 0, 0);   // t=126: drain C127
  KT9(1, 0, 0, 0);   // t=127

  // epilogue: D row=(lane>>4)*4+reg, col=lane&15
  const int orow0 = tm * 128 + wr * 64 + lg * 4;
  const int ocol0 = tn * 256 + wc * 64 + lr;
  float bv[4];
  #pragma unroll
  for (int n = 0; n < 4; ++n) bv[n] = bias[ocol0 + n * 16];
  #pragma unroll
  for (int m = 0; m < 4; ++m) {
    #pragma unroll
    for (int r = 0; r < 4; ++r) {
      float* op = out + (size_t)(orow0 + m * 16 + r) * N_DIM + ocol0;
      #pragma unroll
      for (int n = 0; n < 4; ++n) op[n * 16] = acc[m][n][r] + bv[n];
    }
  }
}

// ===========================================================================
// PATH B fallback (round-1 verified): 128^2 tile, fp32 A reg-staged.
// ===========================================================================
__global__ __launch_bounds__(256) void dequant_f(
    const int* __restrict__ qw, const float* __restrict__ s1,
    const float* __restrict__ s2, bf16* __restrict__ Bp)
{
  const int t = blockIdx.x * 256 + threadIdx.x;
  const int o = t & 4095;
  const int r = t >> 12;
  const int g = r >> 4;
  const int kt = r >> 2;
  const int kk0 = (r & 3) * 8;
  const uint32_t wbits = (uint32_t)qw[(size_t)r * 4096 + o];
  const float a = s1[g * 4096 + o] * 0.5f;
  const float b = s2[g * 4096 + o] * 0.5f;
  const uint64_t lo = 0x00FFFEFDFCFAF8F4ull;
  const uint64_t hi = 0x0C08060403020100ull;
  union { bf16 h[8]; s16x8 v; } u;
  #pragma unroll
  for (int j = 0; j < 8; ++j) {
    const int q = (wbits >> (4 * j)) & 15;
    const uint64_t pk = (q & 8) ? hi : lo;
    const int c2 = (int)(int8_t)(uint8_t)(pk >> ((q & 7) * 8));
    const float s = (q & 8) ? a : b;
    u.h[j] = __float2bfloat16((float)c2 * s);
  }
  const int nt = o >> 7, col = o & 127;
  bf16* dst = Bp + (((size_t)(nt * 128 + kt) * 128 + col) * 32 + kk0);
  *(s16x8*)dst = u.v;
}

__global__ __launch_bounds__(256) void gemmf_k(
    const float* __restrict__ x, const bf16* __restrict__ Bp,
    const float* __restrict__ bias, float* __restrict__ out)
{
  __shared__ bf16 As[2][4096];
  __shared__ bf16 Bs[2][4096];

  const int id  = blockIdx.x;
  const int swz = (id & 7) * 256 + (id >> 3);
  const int tm  = swz >> 5;
  const int tn  = swz & 31;
  const int tid = threadIdx.x;
  const int lane = tid & 63;
  const int w   = tid >> 6;
  const int wr  = (w >> 1) * 64;
  const int wc  = (w & 1) * 64;
  const int lr  = lane & 15;
  const int lg  = lane >> 4;

  f32x4 acc[4][4];
  #pragma unroll
  for (int m = 0; m < 4; ++m)
    #pragma unroll
    for (int n = 0; n < 4; ++n) acc[m][n] = (f32x4){0.f, 0.f, 0.f, 0.f};

  const bf16* bsrc = Bp + ((size_t)tn << 19);
  const float* asrc_f = x + ((size_t)(tm * 128 + (tid >> 1)) << 12) + (tid & 1) * 16;
  float areg[16];

  auto stageB = [&](int kt, int buf) {
    const bf16* bs = bsrc + ((size_t)kt << 12);
    gll16(bs + tid * 8,        &Bs[buf][tid * 8]);
    gll16(bs + 2048 + tid * 8, &Bs[buf][2048 + tid * 8]);
  };
  auto loadA = [&](int kt) {
    const float* s = asrc_f + ((size_t)kt << 5);
    #pragma unroll
    for (int i = 0; i < 4; ++i)
      *(f32x4*)(areg + i * 4) = *(const f32x4*)(s + i * 4);
  };
  auto writeA = [&](int buf) {
    union { bf16 h[16]; s16x8 v[2]; } u;
    #pragma unroll
    for (int i = 0; i < 16; ++i) u.h[i] = __float2bfloat16(areg[i]);
    bf16* d = &As[buf][(tid >> 1) * 32 + (tid & 1) * 16];
    *(s16x8*)d = u.v[0];
    *(s16x8*)(d + 8) = u.v[1];
  };
  auto compute = [&](int buf) {
    s16x8 af[4], bv[4];
    #pragma unroll
    for (int m = 0; m < 4; ++m)
      af[m] = *(const s16x8*)(&As[buf][(wr + m * 16 + lr) * 32 + lg * 8]);
    #pragma unroll
    for (int n = 0; n < 4; ++n)
      bv[n] = *(const s16x8*)(&Bs[buf][(wc + n * 16 + lr) * 32 + lg * 8]);
    #pragma unroll
    for (int m = 0; m < 4; ++m)
      #pragma unroll
      for (int n = 0; n < 4; ++n)
        acc[m][n] = __builtin_amdgcn_mfma_f32_16x16x32_bf16(af[m], bv[n],
                                                            acc[m][n], 0, 0, 0);
  };

  stageB(0, 0);
  loadA(0);
  writeA(0);
  __syncthreads();

  #pragma unroll 2
  for (int kt = 0; kt < 128; ++kt) {
    const int buf = kt & 1;
    if (kt + 1 < 128) {
      stageB(kt + 1, buf ^ 1);
      loadA(kt + 1);
    }
    compute(buf);
    if (kt + 1 < 128) writeA(buf ^ 1);
    __syncthreads();
  }

  const int orow0 = tm * 128 + wr + lg * 4;
  const int ocol0 = tn * 128 + wc + lr;
  float bvv[4];
  #pragma unroll
  for (int n = 0; n < 4; ++n) bvv[n] = bias[ocol0 + n * 16];
  #pragma unroll
  for (int m = 0; m < 4; ++m) {
    #pragma unroll
    for (int r = 0; r < 4; ++r) {
      float* op = out + (size_t)(orow0 + m * 16 + r) * N_DIM + ocol0;
      #pragma unroll
      for (int n = 0; n < 4; ++n)
        op[n * 16] = acc[m][n][r] + bvv[n];
    }
  }
}

extern "C" void kernel_launch(void* const* d_in, const int* in_sizes, int n_in,
                              void* d_out, int out_size, void* d_ws, size_t ws_size,
                              hipStream_t stream) {
  const float* x    = (const float*)d_in[0];
  const int*   qw   = (const int*)d_in[1];
  const float* s1   = (const float*)d_in[2];
  const float* s2   = (const float*)d_in[3];
  const float* bias = (const float*)d_in[4];
  float* out = (float*)d_out;

  const size_t BP_BYTES = (size_t)K_DIM * N_DIM * 2;    // 32 MiB
  const size_t XB_BYTES = (size_t)M_ROWS * K_DIM * 2;   // 64 MiB
  bf16* Bp = (bf16*)d_ws;

  if (ws_size >= BP_BYTES + XB_BYTES) {
    bf16* Ap = (bf16*)((char*)d_ws + BP_BYTES);
    prep_k<<<dim3(18432), dim3(256), 0, stream>>>(qw, s1, s2, x, Bp, Ap);
    gemm9_k<<<dim3(1024), dim3(512), 0, stream>>>(Ap, Bp, bias, out);
  } else {
    dequant_f<<<dim3(8192), dim3(256), 0, stream>>>(qw, s1, s2, Bp);
    gemmf_k<<<dim3(2048), dim3(256), 0, stream>>>(x, Bp, bias, out);
  }
}